// Round 7
// baseline (638.642 us; speedup 1.0000x reference)
//
#include <hip/hip_runtime.h>
#include <hip/hip_bf16.h>
#include <cstring>
#include <cstdint>

#define N_NODES 100000
#define N_EDGES 1600000
#define HID 128
#define TOT (N_NODES * HID)   // 12,800,000
#define GEMM_GRID_C 782       // (N_NODES + 127) / 128
#define SCAT_GRID_C 6250      // N_EDGES / 256

// ---------------- workspace layout (bytes) ----------------
// aggbuf region      @ 0           51,200,000
//   ALIASED: t1 bf16[N,128] in [0, 25.6MB) during layer 1 (dead after k_agg_h);
//            ha bf16[N,128] in [0, 25.6MB) during layer 2 (written by k_agg_bf16);
//            rank int[E]    in [25.6MB, 32MB) during CSR build (dead after scatter)
// hbf     bf16[N,128]   @ 51,200,000  25,600,000
// counts  int [N]       @ 76,800,000     400,000
// partial int [N]       @ 77,200,000     400,000
// bsum    int [512]     @ 77,600,000       2,048
// offsets int [N+1]     @ 77,602,048     400,128
// wmu_t   bf16[128][128]@ 78,002,176      32,768
// wlv_t   bf16[128][128]@ 78,034,944      32,768
// dinv    f32 [N]       @ 78,402,176     400,000
// sorted  int2[E]       @ 78,802,176  12,800,000
// total ~91.6 MB

// NOTE (round-3): fusing threefry into a GEMM epilogue with 64 live acc regs spills.
//   Round-7 fusion avoids it: rolled nt-loop => only 16 live acc regs, LDS-staged
//   epilogue so the sampling loop uses dynamic LDS indexing (no reg-array).
// NOTE (round-4): scatter is write-amplification-bound: 101MB HBM writes for a
//   12.8MB payload even though sorted[] fits aggregate L2 => cross-XCD line
//   sharing (each 64B line dirtied in ~8 per-XCD L2s, each writing back 64B).
//   Round-7: nontemporal stores to stream bytes past L2 allocation.
// NOTE (round-5): f32 VALU gemm pair was FMA-issue-bound; MFMA (16x16x32 bf16,
//   B^T pattern, no LDS) verified with identical absmax.

// ---------------- helpers ----------------
typedef __bf16 bf16x8 __attribute__((ext_vector_type(8)));
typedef float f32x4 __attribute__((ext_vector_type(4)));

__device__ __forceinline__ float2 ld2(const float* p) { return *(const float2*)p; }
__device__ __forceinline__ float2 ld2(const __hip_bfloat16* p) {
    const __hip_bfloat162 h = *(const __hip_bfloat162*)p;
    return make_float2(__bfloat162float(h.x), __bfloat162float(h.y));
}

__device__ __forceinline__ void store8(float* p, const float* v) {
    *(float4*)(p)     = make_float4(v[0], v[1], v[2], v[3]);
    *(float4*)(p + 4) = make_float4(v[4], v[5], v[6], v[7]);
}
__device__ __forceinline__ void store8(__hip_bfloat16* p, const float* v) {
    union { unsigned short us[8]; uint4 q; } u;
#pragma unroll
    for (int i = 0; i < 8; ++i) {
        __hip_bfloat16 b = __float2bfloat16(v[i]);
        unsigned short raw;
        memcpy(&raw, &b, 2);
        u.us[i] = raw;
    }
    *(uint4*)p = u.q;
}

// ---------------- CSR build ----------------
__global__ void k_count_rank(const int* __restrict__ dst, int* __restrict__ counts,
                             int* __restrict__ rank) {
    int e = blockIdx.x * 256 + threadIdx.x;
    if (e < N_EDGES) rank[e] = atomicAdd(&counts[dst[e]], 1);
}

__global__ void k_scan_block(const int* __restrict__ counts, int* __restrict__ partial,
                             int* __restrict__ bsum) {
    __shared__ int s[256];
    int i = blockIdx.x * 256 + threadIdx.x;
    int v = (i < N_NODES) ? counts[i] : 0;
    s[threadIdx.x] = v;
    __syncthreads();
    for (int off = 1; off < 256; off <<= 1) {
        int t = (threadIdx.x >= off) ? s[threadIdx.x - off] : 0;
        __syncthreads();
        s[threadIdx.x] += t;
        __syncthreads();
    }
    if (i < N_NODES) partial[i] = s[threadIdx.x] - v;   // exclusive within block
    if (threadIdx.x == 255) bsum[blockIdx.x] = s[255];
}

__global__ void k_scan_sums(int* __restrict__ bsum, int nb) {
    __shared__ int s[512];
    int v = (threadIdx.x < nb) ? bsum[threadIdx.x] : 0;
    s[threadIdx.x] = v;
    __syncthreads();
    for (int off = 1; off < 512; off <<= 1) {
        int t = (threadIdx.x >= off) ? s[threadIdx.x - off] : 0;
        __syncthreads();
        s[threadIdx.x] += t;
        __syncthreads();
    }
    if (threadIdx.x < nb) bsum[threadIdx.x] = s[threadIdx.x] - v;  // exclusive
}

__global__ void k_finalize(const int* __restrict__ counts, const int* __restrict__ partial,
                           const int* __restrict__ bsum, int* __restrict__ offsets,
                           float* __restrict__ dinv) {
    int i = blockIdx.x * 256 + threadIdx.x;
    if (i < N_NODES) {
        int o = partial[i] + bsum[blockIdx.x];
        offsets[i] = o;
        dinv[i] = rsqrtf((float)(counts[i] + 1));  // deg = in-degree + self loop
    }
    if (i == 0) offsets[N_NODES] = N_EDGES;
}

// W[128][128] f32 (rows = k) -> Wt[128][128] bf16 (rows = n), for both matrices
__global__ void k_prep_w(const float* __restrict__ Wmu, const float* __restrict__ Wlv,
                         __hip_bfloat16* __restrict__ wmu_t,
                         __hip_bfloat16* __restrict__ wlv_t) {
    int idx = blockIdx.x * 256 + threadIdx.x;
    if (idx < 128 * 128) {
        int k = idx >> 7, n = idx & 127;
        wmu_t[n * 128 + k] = __float2bfloat16(Wmu[idx]);
        wlv_t[n * 128 + k] = __float2bfloat16(Wlv[idx]);
    }
}

// ---------------- fat kernel: gemm1 (t1 = x@W1, bf16) || scatter ----------------
__global__ __launch_bounds__(256) void k_gemm1_scatter(
    const float* __restrict__ A, const float* __restrict__ W,
    __hip_bfloat16* __restrict__ out,
    const int* __restrict__ src, const int* __restrict__ dst,
    const int* __restrict__ rank, const int* __restrict__ offsets,
    const float* __restrict__ dinv, int2* __restrict__ sorted) {
    __shared__ float Wl[16][128];
    __shared__ float Al[128][16];

    if (blockIdx.x >= GEMM_GRID_C) {
        // ---- scatter path: nontemporal 8B stores (bypass L2 allocation; the
        // sorted payload is 12.8MB but round-4/5 measured 101MB HBM writes from
        // cross-XCD partial-line writebacks) ----
        int e = (blockIdx.x - GEMM_GRID_C) * 256 + threadIdx.x;
        if (e < N_EDGES) {
            int s = src[e], d = dst[e];
            int pos = offsets[d] + rank[e];
            float c = dinv[s] * dinv[d];
            unsigned long long v =
                ((unsigned long long)(unsigned)__float_as_int(c) << 32) |
                (unsigned long long)(unsigned)s;
            __builtin_nontemporal_store(v, (unsigned long long*)(sorted + pos));
        }
        return;
    }

    // ---- gemm path ----
    int t = threadIdx.x;
    int R = blockIdx.x * 128;
    int tx = t & 15, ty = t >> 4;
    int c0 = tx * 8;
    int r0 = ty * 8;
    float acc[8][8] = {};

    for (int k0 = 0; k0 < 128; k0 += 16) {
        {
            const float4* Wg = (const float4*)(W + k0 * 128);
            ((float4*)&Wl[0][0])[t] = Wg[t];
            ((float4*)&Wl[0][0])[t + 256] = Wg[t + 256];
        }
        {
#pragma unroll
            for (int ii = 0; ii < 2; ++ii) {
                int id = t + ii * 256;
                int row = id >> 2, c4 = (id & 3) * 4;
                int gr = R + row;
                float4 v = make_float4(0.f, 0.f, 0.f, 0.f);
                if (gr < N_NODES) v = *(const float4*)(A + (size_t)gr * HID + k0 + c4);
                *(float4*)(&Al[row][c4]) = v;
            }
        }
        __syncthreads();

#pragma unroll
        for (int kk4 = 0; kk4 < 4; ++kk4) {
            float4 av4[8];
#pragma unroll
            for (int j = 0; j < 8; ++j) av4[j] = *(const float4*)(&Al[r0 + j][kk4 * 4]);
            const float* av = (const float*)av4;
#pragma unroll
            for (int kk = 0; kk < 4; ++kk) {
                float4 b0 = *(const float4*)(&Wl[kk4 * 4 + kk][c0]);
                float4 b1 = *(const float4*)(&Wl[kk4 * 4 + kk][c0 + 4]);
#pragma unroll
                for (int j = 0; j < 8; ++j) {
                    float a = av[j * 4 + kk];
                    acc[j][0] = fmaf(a, b0.x, acc[j][0]);
                    acc[j][1] = fmaf(a, b0.y, acc[j][1]);
                    acc[j][2] = fmaf(a, b0.z, acc[j][2]);
                    acc[j][3] = fmaf(a, b0.w, acc[j][3]);
                    acc[j][4] = fmaf(a, b1.x, acc[j][4]);
                    acc[j][5] = fmaf(a, b1.y, acc[j][5]);
                    acc[j][6] = fmaf(a, b1.z, acc[j][6]);
                    acc[j][7] = fmaf(a, b1.w, acc[j][7]);
                }
            }
        }
        __syncthreads();
    }

#pragma unroll
    for (int j = 0; j < 8; ++j) {
        int gr = R + r0 + j;
        if (gr >= N_NODES) continue;
        float v[8];
#pragma unroll
        for (int c = 0; c < 8; ++c) v[c] = acc[j][c];
        store8(out + (size_t)gr * HID + c0, v);
    }
}

// ---------------- aggregation: one wave per node, 2 features per lane ----------------
#define AGG_BATCH(U)                                                              \
    {                                                                             \
        int2 sv[U];                                                               \
        float2 xs[U];                                                             \
        _Pragma("unroll") for (int i = 0; i < U; ++i) sv[i] = sorted[e + i];      \
        _Pragma("unroll") for (int i = 0; i < U; ++i)                             \
            xs[i] = ld2(Xf + (size_t)sv[i].x * HID);                              \
        _Pragma("unroll") for (int i = 0; i < U; ++i) {                           \
            float c = __int_as_float(sv[i].y);                                    \
            a0 = fmaf(c, xs[i].x, a0);                                            \
            a1 = fmaf(c, xs[i].y, a1);                                            \
        }                                                                         \
        e += U;                                                                   \
    }

#define AGG_BATCH_CLAMPED(U)                                                      \
    {                                                                             \
        int2 sv[U];                                                               \
        float2 xs[U];                                                             \
        _Pragma("unroll") for (int i = 0; i < U; ++i) {                           \
            int ee = e + i;                                                       \
            sv[i] = sorted[(ee < e1) ? ee : (e1 - 1)];                            \
        }                                                                         \
        _Pragma("unroll") for (int i = 0; i < U; ++i)                             \
            xs[i] = ld2(Xf + (size_t)sv[i].x * HID);                              \
        _Pragma("unroll") for (int i = 0; i < U; ++i) {                           \
            float c = (e + i < e1) ? __int_as_float(sv[i].y) : 0.f;               \
            a0 = fmaf(c, xs[i].x, a0);                                            \
            a1 = fmaf(c, xs[i].y, a1);                                            \
        }                                                                         \
    }

#define AGG_CORE(XTYPE)                                                           \
    int node = (blockIdx.x * 256 + threadIdx.x) >> 6;                             \
    int lane = threadIdx.x & 63;                                                  \
    if (node >= N_NODES) return;                                                  \
    int f = lane * 2;                                                             \
    const XTYPE* __restrict__ Xf = X + f;                                         \
    float di = dinv[node];                                                        \
    float sc = di * di;                                                           \
    float2 xi = ld2(Xf + (size_t)node * HID);                                     \
    float a0 = sc * xi.x, a1 = sc * xi.y;                                         \
    int e = offsets[node], e1 = offsets[node + 1];                                \
    int rem = e1 - e;                                                             \
    while (rem >= 16) {                                                           \
        AGG_BATCH(16);                                                            \
        rem -= 16;                                                                \
    }                                                                             \
    if (rem > 8) {                                                                \
        AGG_BATCH_CLAMPED(16);                                                    \
    } else if (rem > 0) {                                                         \
        AGG_BATCH_CLAMPED(8);                                                     \
    }

// layer-1 aggregate: gathers t1 (bf16), epilogue h = ELU(agg + b1), writes bf16
__global__ __launch_bounds__(256) void k_agg_h(const __hip_bfloat16* __restrict__ X,
                                               const int* __restrict__ offsets,
                                               const int2* __restrict__ sorted,
                                               const float* __restrict__ dinv,
                                               const float* __restrict__ b1,
                                               __hip_bfloat16* __restrict__ out) {
    AGG_CORE(__hip_bfloat16)
    float v0 = a0 + b1[f];
    float v1 = a1 + b1[f + 1];
    v0 = (v0 > 0.f) ? v0 : expm1f(v0);  // ELU(alpha=1)
    v1 = (v1 > 0.f) ? v1 : expm1f(v1);
    __hip_bfloat162 hb;
    hb.x = __float2bfloat16(v0);
    hb.y = __float2bfloat16(v1);
    *(__hip_bfloat162*)(out + (size_t)node * HID + f) = hb;
}

// layer-2 aggregate: gathers h (bf16), writes bf16 ha (MFMA A-operand)
__global__ __launch_bounds__(256) void k_agg_bf16(const __hip_bfloat16* __restrict__ X,
                                                  const int* __restrict__ offsets,
                                                  const int2* __restrict__ sorted,
                                                  const float* __restrict__ dinv,
                                                  __hip_bfloat16* __restrict__ out) {
    AGG_CORE(__hip_bfloat16)
    __hip_bfloat162 hb;
    hb.x = __float2bfloat16(a0);
    hb.y = __float2bfloat16(a1);
    *(__hip_bfloat162*)(out + (size_t)node * HID + f) = hb;
}

// ---------------- Threefry-2x32 (20 rounds), key = (0, 42) ----------------
__device__ __forceinline__ unsigned rotl32(unsigned x, int r) {
    return (x << r) | (x >> (32 - r));
}

__device__ __forceinline__ void threefry2x32(unsigned x0, unsigned x1, unsigned& o0,
                                             unsigned& o1) {
    const unsigned ks0 = 0u, ks1 = 42u, ks2 = 0x1BD11BDAu ^ 42u;
    x0 += ks0;
    x1 += ks1;
    x0 += x1; x1 = rotl32(x1, 13); x1 ^= x0;
    x0 += x1; x1 = rotl32(x1, 15); x1 ^= x0;
    x0 += x1; x1 = rotl32(x1, 26); x1 ^= x0;
    x0 += x1; x1 = rotl32(x1, 6);  x1 ^= x0;
    x0 += ks1; x1 += ks2 + 1u;
    x0 += x1; x1 = rotl32(x1, 17); x1 ^= x0;
    x0 += x1; x1 = rotl32(x1, 29); x1 ^= x0;
    x0 += x1; x1 = rotl32(x1, 16); x1 ^= x0;
    x0 += x1; x1 = rotl32(x1, 24); x1 ^= x0;
    x0 += ks2; x1 += ks0 + 2u;
    x0 += x1; x1 = rotl32(x1, 13); x1 ^= x0;
    x0 += x1; x1 = rotl32(x1, 15); x1 ^= x0;
    x0 += x1; x1 = rotl32(x1, 26); x1 ^= x0;
    x0 += x1; x1 = rotl32(x1, 6);  x1 ^= x0;
    x0 += ks0; x1 += ks1 + 3u;
    x0 += x1; x1 = rotl32(x1, 17); x1 ^= x0;
    x0 += x1; x1 = rotl32(x1, 29); x1 ^= x0;
    x0 += x1; x1 = rotl32(x1, 16); x1 ^= x0;
    x0 += x1; x1 = rotl32(x1, 24); x1 ^= x0;
    x0 += ks1; x1 += ks2 + 4u;
    x0 += x1; x1 = rotl32(x1, 13); x1 ^= x0;
    x0 += x1; x1 = rotl32(x1, 15); x1 ^= x0;
    x0 += x1; x1 = rotl32(x1, 26); x1 ^= x0;
    x0 += x1; x1 = rotl32(x1, 6);  x1 ^= x0;
    x0 += ks2; x1 += ks0 + 5u;
    o0 = x0;
    o1 = x1;
}

// XLA ErfInv (f32, Giles) — matches CPU XLA expansion used by jax.random.normal.
__device__ __forceinline__ float erfinv_f32(float x) {
    float w = -log1pf(-x * x);
    float p;
    if (w < 5.0f) {
        w -= 2.5f;
        p = 2.81022636e-08f;
        p = fmaf(p, w, 3.43273939e-07f);
        p = fmaf(p, w, -3.5233877e-06f);
        p = fmaf(p, w, -4.39150654e-06f);
        p = fmaf(p, w, 0.00021858087f);
        p = fmaf(p, w, -0.00125372503f);
        p = fmaf(p, w, -0.00417768164f);
        p = fmaf(p, w, 0.246640727f);
        p = fmaf(p, w, 1.50140941f);
    } else {
        w = sqrtf(w) - 3.0f;
        p = -0.000200214257f;
        p = fmaf(p, w, 0.000100950558f);
        p = fmaf(p, w, 0.00134934322f);
        p = fmaf(p, w, -0.00367342844f);
        p = fmaf(p, w, 0.00573950773f);
        p = fmaf(p, w, -0.0076224613f);
        p = fmaf(p, w, 0.00943887047f);
        p = fmaf(p, w, 1.00167406f);
        p = fmaf(p, w, 2.83297682f);
    }
    return p * x;
}

__device__ __forceinline__ float sample_eps(unsigned j) {
    unsigned o0, o1;
    threefry2x32(0u, j, o0, o1);
    unsigned bits = o0 ^ o1;
    float f = __uint_as_float((bits >> 9) | 0x3f800000u) - 1.0f;
    float u = f * 2.0f - 0.99999994f;
    u = fmaxf(u, -0.99999994f);
    return 1.41421356f * erfinv_f32(u);
}

// ---------------- fused MFMA GEMM pair + reparameterize ----------------
// Per block: 128 rows, all 128 cols, BOTH weight matrices, plus z epilogue.
// Spill-safe by design (round-3 lesson): nt loop is ROLLED, so only 4 f32x4
// accumulators (named statics) are live at a time; results staged to LDS; the
// sampling loop indexes LDS dynamically (memory, not registers) with one rolled
// copy of threefry. A rows read once per block (pair kernel read them twice).
__global__ __launch_bounds__(256) void k_gemm2_mfma_sample(
    const __hip_bfloat16* __restrict__ A,
    const __hip_bfloat16* __restrict__ wmu_t, const float* __restrict__ bmu,
    const __hip_bfloat16* __restrict__ wlv_t, const float* __restrict__ blv,
    float* __restrict__ mu, float* __restrict__ lv, float* __restrict__ z) {
    __shared__ float Sm[128][17];  // +1 pad: stage/sample bank-conflict-free
    __shared__ float Sv[128][17];
    int w = threadIdx.x >> 6;        // wave 0..3
    int l = threadIdx.x & 63;
    int l16 = l & 15, lg = l >> 4;
    int bx = blockIdx.x;
    int wrow = bx * 128 + w * 32;

    // A fragments (row-clamped; pad rows harmless): a[mt][ks]
    bf16x8 a[2][4];
#pragma unroll
    for (int mt = 0; mt < 2; ++mt) {
#pragma unroll
        for (int ks = 0; ks < 4; ++ks) {
            int row = wrow + mt * 16 + l16;
            int rr = (row < N_NODES) ? row : (N_NODES - 1);
            a[mt][ks] = *reinterpret_cast<const bf16x8*>(
                A + (size_t)rr * HID + ks * 32 + lg * 8);
        }
    }

#pragma unroll 1
    for (int nt = 0; nt < 8; ++nt) {
        f32x4 am0 = {0.f, 0.f, 0.f, 0.f}, am1 = {0.f, 0.f, 0.f, 0.f};
        f32x4 al0 = {0.f, 0.f, 0.f, 0.f}, al1 = {0.f, 0.f, 0.f, 0.f};
        {
            bf16x8 b[4];
#pragma unroll
            for (int ks = 0; ks < 4; ++ks)
                b[ks] = *reinterpret_cast<const bf16x8*>(
                    wmu_t + (size_t)(nt * 16 + l16) * HID + ks * 32 + lg * 8);
#pragma unroll
            for (int ks = 0; ks < 4; ++ks) {
                am0 = __builtin_amdgcn_mfma_f32_16x16x32_bf16(a[0][ks], b[ks], am0, 0, 0, 0);
                am1 = __builtin_amdgcn_mfma_f32_16x16x32_bf16(a[1][ks], b[ks], am1, 0, 0, 0);
            }
        }
        {
            bf16x8 b[4];
#pragma unroll
            for (int ks = 0; ks < 4; ++ks)
                b[ks] = *reinterpret_cast<const bf16x8*>(
                    wlv_t + (size_t)(nt * 16 + l16) * HID + ks * 32 + lg * 8);
#pragma unroll
            for (int ks = 0; ks < 4; ++ks) {
                al0 = __builtin_amdgcn_mfma_f32_16x16x32_bf16(a[0][ks], b[ks], al0, 0, 0, 0);
                al1 = __builtin_amdgcn_mfma_f32_16x16x32_bf16(a[1][ks], b[ks], al1, 0, 0, 0);
            }
        }
        float bm = bmu[nt * 16 + l16];
        float bv = blv[nt * 16 + l16];
        // stage this column-tile (C/D map: row = lg*4 + r within 16-tile, col = l16)
#pragma unroll
        for (int r = 0; r < 4; ++r) {
            Sm[w * 32 + lg * 4 + r][l16] = am0[r] + bm;
            Sm[w * 32 + 16 + lg * 4 + r][l16] = am1[r] + bm;
            Sv[w * 32 + lg * 4 + r][l16] = al0[r] + bv;
            Sv[w * 32 + 16 + lg * 4 + r][l16] = al1[r] + bv;
        }
        __syncthreads();
        // sample + store this tile (2048 elems / 256 threads)
#pragma unroll 1
        for (int it = 0; it < 8; ++it) {
            int idx = it * 256 + threadIdx.x;
            int row = idx >> 4, c16 = idx & 15;
            int gr = bx * 128 + row;
            if (gr < N_NODES) {
                float m = Sm[row][c16];
                float lval = Sv[row][c16];
                int col = nt * 16 + c16;
                float eps = sample_eps((unsigned)(gr * 128 + col));
                size_t o = (size_t)gr * HID + col;
                mu[o] = m;
                lv[o] = lval;
                z[o] = fmaf(eps, expf(0.5f * lval), m);
            }
        }
        __syncthreads();
    }
}

// ---------------- launch ----------------
extern "C" void kernel_launch(void* const* d_in, const int* in_sizes, int n_in,
                              void* d_out, int out_size, void* d_ws, size_t ws_size,
                              hipStream_t stream) {
    const float* x = (const float*)d_in[0];
    const int* ei = (const int*)d_in[1];
    const float* W1 = (const float*)d_in[2];
    const float* b1 = (const float*)d_in[3];
    const float* Wmu = (const float*)d_in[4];
    const float* bmu = (const float*)d_in[5];
    const float* Wlv = (const float*)d_in[6];
    const float* blv = (const float*)d_in[7];

    float* z = (float*)d_out;
    float* mu = z + (size_t)TOT;
    float* lv = z + 2 * (size_t)TOT;

    char* ws = (char*)d_ws;
    __hip_bfloat16* t1buf = (__hip_bfloat16*)(ws + 0ull);   // layer-1 t1
    __hip_bfloat16* habf = (__hip_bfloat16*)(ws + 0ull);    // layer-2 agg (reuses)
    int* rank = (int*)(ws + 25600000ull);                   // dead after scatter
    __hip_bfloat16* hbf = (__hip_bfloat16*)(ws + 51200000ull);
    int* counts = (int*)(ws + 76800000ull);
    int* partial = (int*)(ws + 77200000ull);
    int* bsum = (int*)(ws + 77600000ull);
    int* offsets = (int*)(ws + 77602048ull);
    __hip_bfloat16* wmu_t = (__hip_bfloat16*)(ws + 78002176ull);
    __hip_bfloat16* wlv_t = (__hip_bfloat16*)(ws + 78034944ull);
    float* dinv = (float*)(ws + 78402176ull);
    int2* sorted = (int2*)(ws + 78802176ull);

    const int* src = ei;
    const int* dst = ei + N_EDGES;

    const int NBLK = (N_NODES + 255) / 256;  // 391
    const int AGG_GRID = (N_NODES * 64 + 255) / 256;

    hipMemsetAsync(counts, 0, N_NODES * sizeof(int), stream);
    k_prep_w<<<64, 256, 0, stream>>>(Wmu, Wlv, wmu_t, wlv_t);
    k_count_rank<<<SCAT_GRID_C, 256, 0, stream>>>(dst, counts, rank);
    k_scan_block<<<NBLK, 256, 0, stream>>>(counts, partial, bsum);
    k_scan_sums<<<1, 512, 0, stream>>>(bsum, NBLK);
    k_finalize<<<NBLK, 256, 0, stream>>>(counts, partial, bsum, offsets, dinv);

    // fat launch: t1 = x @ W1 (bf16, no bias) co-scheduled with edge scatter (nt)
    k_gemm1_scatter<<<GEMM_GRID_C + SCAT_GRID_C, 256, 0, stream>>>(
        x, W1, t1buf, src, dst, rank, offsets, dinv, sorted);

    // layer 1: h = ELU(S·t1 + b1) (bf16)
    k_agg_h<<<AGG_GRID, 256, 0, stream>>>(t1buf, offsets, sorted, dinv, b1, hbf);

    // layer 2: ha = S·h (bf16, overwrites t1/rank region); mu+lv+z fused MFMA
    k_agg_bf16<<<AGG_GRID, 256, 0, stream>>>(hbf, offsets, sorted, dinv, habf);
    k_gemm2_mfma_sample<<<GEMM_GRID_C, 256, 0, stream>>>(habf, wmu_t, bmu, wlv_t, blv,
                                                         mu, lv, z);
}

// Round 8
// 592.745 us; speedup vs baseline: 1.0774x; 1.0774x over previous
//
#include <hip/hip_runtime.h>
#include <hip/hip_bf16.h>
#include <cstring>
#include <cstdint>

#define N_NODES 100000
#define N_EDGES 1600000
#define HID 128
#define TOT (N_NODES * HID)   // 12,800,000
#define GEMM_GRID_C 782       // (N_NODES + 127) / 128
#define SCAT_GRID_C 6250      // N_EDGES / 256

// ---------------- workspace layout (bytes) ----------------
// aggbuf region      @ 0           51,200,000
//   ALIASED: t1 bf16[N,128] in [0, 25.6MB) during layer 1 (dead after k_agg_h);
//            ha bf16[N,128] in [0, 25.6MB) during layer 2 (written by k_agg_bf16);
//            rank int[E]    in [25.6MB, 32MB) during CSR build (dead after scatter)
// hbf     bf16[N,128]   @ 51,200,000  25,600,000
// counts  int [N]       @ 76,800,000     400,000
// partial int [N]       @ 77,200,000     400,000
// bsum    int [512]     @ 77,600,000       2,048
// offsets int [N+1]     @ 77,602,048     400,128
// wmu_t   bf16[128][128]@ 78,002,176      32,768
// wlv_t   bf16[128][128]@ 78,034,944      32,768
// dinv    f32 [N]       @ 78,402,176     400,000
// sorted  int2[E]       @ 78,802,176  12,800,000
// total ~91.6 MB

// NOTE (rounds 2/3/7, closed): fusing threefry/erfinv/exp into GEMM epilogues loses
//   every time — either acc spills (r3) or barrier-partitioned VALU serialization at
//   low block count (r7: 131us vs 63us split). Sampling stays a standalone pass.
// NOTE (round-4): scatter is 64B-line write-amplification-bound (101MB writes for
//   12.8MB payload, cross-XCD partial-line writebacks). round-7 measured
//   nontemporal stores recover ~15us. Keep nt.
// NOTE (round-5): MFMA pair (16x16x32 bf16, B^T pattern, no LDS) verified, ~35us.
// NOTE (round-8): fat kernel re-paired: gemm1 || count_rank (both ready at t=0);
//   scatter standalone after the scan chain (it needs offsets anyway).

// ---------------- helpers ----------------
typedef __bf16 bf16x8 __attribute__((ext_vector_type(8)));
typedef float f32x4 __attribute__((ext_vector_type(4)));

__device__ __forceinline__ float2 ld2(const float* p) { return *(const float2*)p; }
__device__ __forceinline__ float2 ld2(const __hip_bfloat16* p) {
    const __hip_bfloat162 h = *(const __hip_bfloat162*)p;
    return make_float2(__bfloat162float(h.x), __bfloat162float(h.y));
}

__device__ __forceinline__ void store8(float* p, const float* v) {
    *(float4*)(p)     = make_float4(v[0], v[1], v[2], v[3]);
    *(float4*)(p + 4) = make_float4(v[4], v[5], v[6], v[7]);
}
__device__ __forceinline__ void store8(__hip_bfloat16* p, const float* v) {
    union { unsigned short us[8]; uint4 q; } u;
#pragma unroll
    for (int i = 0; i < 8; ++i) {
        __hip_bfloat16 b = __float2bfloat16(v[i]);
        unsigned short raw;
        memcpy(&raw, &b, 2);
        u.us[i] = raw;
    }
    *(uint4*)p = u.q;
}

// ---------------- CSR build ----------------
__global__ void k_scan_block(const int* __restrict__ counts, int* __restrict__ partial,
                             int* __restrict__ bsum) {
    __shared__ int s[256];
    int i = blockIdx.x * 256 + threadIdx.x;
    int v = (i < N_NODES) ? counts[i] : 0;
    s[threadIdx.x] = v;
    __syncthreads();
    for (int off = 1; off < 256; off <<= 1) {
        int t = (threadIdx.x >= off) ? s[threadIdx.x - off] : 0;
        __syncthreads();
        s[threadIdx.x] += t;
        __syncthreads();
    }
    if (i < N_NODES) partial[i] = s[threadIdx.x] - v;   // exclusive within block
    if (threadIdx.x == 255) bsum[blockIdx.x] = s[255];
}

__global__ void k_scan_sums(int* __restrict__ bsum, int nb) {
    __shared__ int s[512];
    int v = (threadIdx.x < nb) ? bsum[threadIdx.x] : 0;
    s[threadIdx.x] = v;
    __syncthreads();
    for (int off = 1; off < 512; off <<= 1) {
        int t = (threadIdx.x >= off) ? s[threadIdx.x - off] : 0;
        __syncthreads();
        s[threadIdx.x] += t;
        __syncthreads();
    }
    if (threadIdx.x < nb) bsum[threadIdx.x] = s[threadIdx.x] - v;  // exclusive
}

__global__ void k_finalize(const int* __restrict__ counts, const int* __restrict__ partial,
                           const int* __restrict__ bsum, int* __restrict__ offsets,
                           float* __restrict__ dinv) {
    int i = blockIdx.x * 256 + threadIdx.x;
    if (i < N_NODES) {
        int o = partial[i] + bsum[blockIdx.x];
        offsets[i] = o;
        dinv[i] = rsqrtf((float)(counts[i] + 1));  // deg = in-degree + self loop
    }
    if (i == 0) offsets[N_NODES] = N_EDGES;
}

// W[128][128] f32 (rows = k) -> Wt[128][128] bf16 (rows = n), for both matrices
__global__ void k_prep_w(const float* __restrict__ Wmu, const float* __restrict__ Wlv,
                         __hip_bfloat16* __restrict__ wmu_t,
                         __hip_bfloat16* __restrict__ wlv_t) {
    int idx = blockIdx.x * 256 + threadIdx.x;
    if (idx < 128 * 128) {
        int k = idx >> 7, n = idx & 127;
        wmu_t[n * 128 + k] = __float2bfloat16(Wmu[idx]);
        wlv_t[n * 128 + k] = __float2bfloat16(Wlv[idx]);
    }
}

// ---------------- fat kernel: gemm1 (t1 = x@W1, bf16) || count_rank ----------------
// Both inputs are ready at t=0; gemm1 is VALU/LDS-bound, count_rank is
// atomic/memory-bound — complementary pipes.
__global__ __launch_bounds__(256) void k_gemm1_count(
    const float* __restrict__ A, const float* __restrict__ W,
    __hip_bfloat16* __restrict__ out,
    const int* __restrict__ dst, int* __restrict__ counts, int* __restrict__ rank) {
    __shared__ float Wl[16][128];
    __shared__ float Al[128][16];

    if (blockIdx.x >= GEMM_GRID_C) {
        // ---- count path: per-edge rank = atomic return ----
        int e = (blockIdx.x - GEMM_GRID_C) * 256 + threadIdx.x;
        if (e < N_EDGES) rank[e] = atomicAdd(&counts[dst[e]], 1);
        return;
    }

    // ---- gemm path ----
    int t = threadIdx.x;
    int R = blockIdx.x * 128;
    int tx = t & 15, ty = t >> 4;
    int c0 = tx * 8;
    int r0 = ty * 8;
    float acc[8][8] = {};

    for (int k0 = 0; k0 < 128; k0 += 16) {
        {
            const float4* Wg = (const float4*)(W + k0 * 128);
            ((float4*)&Wl[0][0])[t] = Wg[t];
            ((float4*)&Wl[0][0])[t + 256] = Wg[t + 256];
        }
        {
#pragma unroll
            for (int ii = 0; ii < 2; ++ii) {
                int id = t + ii * 256;
                int row = id >> 2, c4 = (id & 3) * 4;
                int gr = R + row;
                float4 v = make_float4(0.f, 0.f, 0.f, 0.f);
                if (gr < N_NODES) v = *(const float4*)(A + (size_t)gr * HID + k0 + c4);
                *(float4*)(&Al[row][c4]) = v;
            }
        }
        __syncthreads();

#pragma unroll
        for (int kk4 = 0; kk4 < 4; ++kk4) {
            float4 av4[8];
#pragma unroll
            for (int j = 0; j < 8; ++j) av4[j] = *(const float4*)(&Al[r0 + j][kk4 * 4]);
            const float* av = (const float*)av4;
#pragma unroll
            for (int kk = 0; kk < 4; ++kk) {
                float4 b0 = *(const float4*)(&Wl[kk4 * 4 + kk][c0]);
                float4 b1 = *(const float4*)(&Wl[kk4 * 4 + kk][c0 + 4]);
#pragma unroll
                for (int j = 0; j < 8; ++j) {
                    float a = av[j * 4 + kk];
                    acc[j][0] = fmaf(a, b0.x, acc[j][0]);
                    acc[j][1] = fmaf(a, b0.y, acc[j][1]);
                    acc[j][2] = fmaf(a, b0.z, acc[j][2]);
                    acc[j][3] = fmaf(a, b0.w, acc[j][3]);
                    acc[j][4] = fmaf(a, b1.x, acc[j][4]);
                    acc[j][5] = fmaf(a, b1.y, acc[j][5]);
                    acc[j][6] = fmaf(a, b1.z, acc[j][6]);
                    acc[j][7] = fmaf(a, b1.w, acc[j][7]);
                }
            }
        }
        __syncthreads();
    }

#pragma unroll
    for (int j = 0; j < 8; ++j) {
        int gr = R + r0 + j;
        if (gr >= N_NODES) continue;
        float v[8];
#pragma unroll
        for (int c = 0; c < 8; ++c) v[c] = acc[j][c];
        store8(out + (size_t)gr * HID + c0, v);
    }
}

// ---------------- scatter: deterministic positions, nontemporal stores ----------------
__global__ __launch_bounds__(256) void k_scatter(
    const int* __restrict__ src, const int* __restrict__ dst,
    const int* __restrict__ rank, const int* __restrict__ offsets,
    const float* __restrict__ dinv, int2* __restrict__ sorted) {
    int e = blockIdx.x * 256 + threadIdx.x;
    if (e < N_EDGES) {
        int s = src[e], d = dst[e];
        int pos = offsets[d] + rank[e];
        float c = dinv[s] * dinv[d];
        unsigned long long v =
            ((unsigned long long)(unsigned)__float_as_int(c) << 32) |
            (unsigned long long)(unsigned)s;
        __builtin_nontemporal_store(v, (unsigned long long*)(sorted + pos));
    }
}

// ---------------- aggregation: one wave per node, 2 features per lane ----------------
#define AGG_BATCH(U)                                                              \
    {                                                                             \
        int2 sv[U];                                                               \
        float2 xs[U];                                                             \
        _Pragma("unroll") for (int i = 0; i < U; ++i) sv[i] = sorted[e + i];      \
        _Pragma("unroll") for (int i = 0; i < U; ++i)                             \
            xs[i] = ld2(Xf + (size_t)sv[i].x * HID);                              \
        _Pragma("unroll") for (int i = 0; i < U; ++i) {                           \
            float c = __int_as_float(sv[i].y);                                    \
            a0 = fmaf(c, xs[i].x, a0);                                            \
            a1 = fmaf(c, xs[i].y, a1);                                            \
        }                                                                         \
        e += U;                                                                   \
    }

#define AGG_BATCH_CLAMPED(U)                                                      \
    {                                                                             \
        int2 sv[U];                                                               \
        float2 xs[U];                                                             \
        _Pragma("unroll") for (int i = 0; i < U; ++i) {                           \
            int ee = e + i;                                                       \
            sv[i] = sorted[(ee < e1) ? ee : (e1 - 1)];                            \
        }                                                                         \
        _Pragma("unroll") for (int i = 0; i < U; ++i)                             \
            xs[i] = ld2(Xf + (size_t)sv[i].x * HID);                              \
        _Pragma("unroll") for (int i = 0; i < U; ++i) {                           \
            float c = (e + i < e1) ? __int_as_float(sv[i].y) : 0.f;               \
            a0 = fmaf(c, xs[i].x, a0);                                            \
            a1 = fmaf(c, xs[i].y, a1);                                            \
        }                                                                         \
    }

#define AGG_CORE(XTYPE)                                                           \
    int node = (blockIdx.x * 256 + threadIdx.x) >> 6;                             \
    int lane = threadIdx.x & 63;                                                  \
    if (node >= N_NODES) return;                                                  \
    int f = lane * 2;                                                             \
    const XTYPE* __restrict__ Xf = X + f;                                         \
    float di = dinv[node];                                                        \
    float sc = di * di;                                                           \
    float2 xi = ld2(Xf + (size_t)node * HID);                                     \
    float a0 = sc * xi.x, a1 = sc * xi.y;                                         \
    int e = offsets[node], e1 = offsets[node + 1];                                \
    int rem = e1 - e;                                                             \
    while (rem >= 16) {                                                           \
        AGG_BATCH(16);                                                            \
        rem -= 16;                                                                \
    }                                                                             \
    if (rem > 8) {                                                                \
        AGG_BATCH_CLAMPED(16);                                                    \
    } else if (rem > 0) {                                                         \
        AGG_BATCH_CLAMPED(8);                                                     \
    }

// layer-1 aggregate: gathers t1 (bf16), epilogue h = ELU(agg + b1), writes bf16
__global__ __launch_bounds__(256) void k_agg_h(const __hip_bfloat16* __restrict__ X,
                                               const int* __restrict__ offsets,
                                               const int2* __restrict__ sorted,
                                               const float* __restrict__ dinv,
                                               const float* __restrict__ b1,
                                               __hip_bfloat16* __restrict__ out) {
    AGG_CORE(__hip_bfloat16)
    float v0 = a0 + b1[f];
    float v1 = a1 + b1[f + 1];
    v0 = (v0 > 0.f) ? v0 : expm1f(v0);  // ELU(alpha=1)
    v1 = (v1 > 0.f) ? v1 : expm1f(v1);
    __hip_bfloat162 hb;
    hb.x = __float2bfloat16(v0);
    hb.y = __float2bfloat16(v1);
    *(__hip_bfloat162*)(out + (size_t)node * HID + f) = hb;
}

// layer-2 aggregate: gathers h (bf16), writes bf16 ha (MFMA A-operand)
__global__ __launch_bounds__(256) void k_agg_bf16(const __hip_bfloat16* __restrict__ X,
                                                  const int* __restrict__ offsets,
                                                  const int2* __restrict__ sorted,
                                                  const float* __restrict__ dinv,
                                                  __hip_bfloat16* __restrict__ out) {
    AGG_CORE(__hip_bfloat16)
    __hip_bfloat162 hb;
    hb.x = __float2bfloat16(a0);
    hb.y = __float2bfloat16(a1);
    *(__hip_bfloat162*)(out + (size_t)node * HID + f) = hb;
}

// ---------------- MFMA GEMM pair: mu and lv in one launch (round-6 proven) ----------
__global__ __launch_bounds__(256) void k_gemm_pair_mfma(
    const __hip_bfloat16* __restrict__ A,
    const __hip_bfloat16* __restrict__ wmu_t, const float* __restrict__ bmu,
    const __hip_bfloat16* __restrict__ wlv_t, const float* __restrict__ blv,
    float* __restrict__ mu, float* __restrict__ lv) {
    int which = (blockIdx.x >= GEMM_GRID_C);
    const __hip_bfloat16* __restrict__ wt = which ? wlv_t : wmu_t;
    const float* __restrict__ bias = which ? blv : bmu;
    float* __restrict__ out = which ? lv : mu;
    int bx = which ? (blockIdx.x - GEMM_GRID_C) : blockIdx.x;

    int w = threadIdx.x >> 6;        // wave 0..3
    int l = threadIdx.x & 63;
    int l16 = l & 15, lg = l >> 4;   // lane-in-16, group 0..3
    int wrow = bx * 128 + w * 32;    // wave's first output row

    bf16x8 a[2][4];
#pragma unroll
    for (int mt = 0; mt < 2; ++mt) {
#pragma unroll
        for (int ks = 0; ks < 4; ++ks) {
            int row = wrow + mt * 16 + l16;
            int rr = (row < N_NODES) ? row : (N_NODES - 1);  // clamp: pad rows harmless
            a[mt][ks] = *reinterpret_cast<const bf16x8*>(
                A + (size_t)rr * HID + ks * 32 + lg * 8);
        }
    }

    f32x4 acc[2][8];
#pragma unroll
    for (int mt = 0; mt < 2; ++mt)
#pragma unroll
        for (int nt = 0; nt < 8; ++nt) acc[mt][nt] = (f32x4){0.f, 0.f, 0.f, 0.f};

#pragma unroll
    for (int nt = 0; nt < 8; ++nt) {
        bf16x8 b[4];
#pragma unroll
        for (int ks = 0; ks < 4; ++ks)
            b[ks] = *reinterpret_cast<const bf16x8*>(
                wt + (size_t)(nt * 16 + l16) * HID + ks * 32 + lg * 8);
#pragma unroll
        for (int ks = 0; ks < 4; ++ks) {
            acc[0][nt] = __builtin_amdgcn_mfma_f32_16x16x32_bf16(a[0][ks], b[ks],
                                                                acc[0][nt], 0, 0, 0);
            acc[1][nt] = __builtin_amdgcn_mfma_f32_16x16x32_bf16(a[1][ks], b[ks],
                                                                acc[1][nt], 0, 0, 0);
        }
    }

#pragma unroll
    for (int nt = 0; nt < 8; ++nt) {
        float bc = bias[nt * 16 + l16];
#pragma unroll
        for (int mt = 0; mt < 2; ++mt) {
#pragma unroll
            for (int r = 0; r < 4; ++r) {
                int gr = wrow + mt * 16 + lg * 4 + r;
                if (gr < N_NODES)
                    out[(size_t)gr * HID + nt * 16 + l16] = acc[mt][nt][r] + bc;
            }
        }
    }
}

// ---------------- Threefry-2x32 (20 rounds), key = (0, 42) ----------------
__device__ __forceinline__ unsigned rotl32(unsigned x, int r) {
    return (x << r) | (x >> (32 - r));
}

__device__ __forceinline__ void threefry2x32(unsigned x0, unsigned x1, unsigned& o0,
                                             unsigned& o1) {
    const unsigned ks0 = 0u, ks1 = 42u, ks2 = 0x1BD11BDAu ^ 42u;
    x0 += ks0;
    x1 += ks1;
    x0 += x1; x1 = rotl32(x1, 13); x1 ^= x0;
    x0 += x1; x1 = rotl32(x1, 15); x1 ^= x0;
    x0 += x1; x1 = rotl32(x1, 26); x1 ^= x0;
    x0 += x1; x1 = rotl32(x1, 6);  x1 ^= x0;
    x0 += ks1; x1 += ks2 + 1u;
    x0 += x1; x1 = rotl32(x1, 17); x1 ^= x0;
    x0 += x1; x1 = rotl32(x1, 29); x1 ^= x0;
    x0 += x1; x1 = rotl32(x1, 16); x1 ^= x0;
    x0 += x1; x1 = rotl32(x1, 24); x1 ^= x0;
    x0 += ks2; x1 += ks0 + 2u;
    x0 += x1; x1 = rotl32(x1, 13); x1 ^= x0;
    x0 += x1; x1 = rotl32(x1, 15); x1 ^= x0;
    x0 += x1; x1 = rotl32(x1, 26); x1 ^= x0;
    x0 += x1; x1 = rotl32(x1, 6);  x1 ^= x0;
    x0 += ks0; x1 += ks1 + 3u;
    x0 += x1; x1 = rotl32(x1, 17); x1 ^= x0;
    x0 += x1; x1 = rotl32(x1, 29); x1 ^= x0;
    x0 += x1; x1 = rotl32(x1, 16); x1 ^= x0;
    x0 += x1; x1 = rotl32(x1, 24); x1 ^= x0;
    x0 += ks1; x1 += ks2 + 4u;
    x0 += x1; x1 = rotl32(x1, 13); x1 ^= x0;
    x0 += x1; x1 = rotl32(x1, 15); x1 ^= x0;
    x0 += x1; x1 = rotl32(x1, 26); x1 ^= x0;
    x0 += x1; x1 = rotl32(x1, 6);  x1 ^= x0;
    x0 += ks2; x1 += ks0 + 5u;
    o0 = x0;
    o1 = x1;
}

// XLA ErfInv (f32, Giles) — matches CPU XLA expansion used by jax.random.normal.
__device__ __forceinline__ float erfinv_f32(float x) {
    float w = -log1pf(-x * x);
    float p;
    if (w < 5.0f) {
        w -= 2.5f;
        p = 2.81022636e-08f;
        p = fmaf(p, w, 3.43273939e-07f);
        p = fmaf(p, w, -3.5233877e-06f);
        p = fmaf(p, w, -4.39150654e-06f);
        p = fmaf(p, w, 0.00021858087f);
        p = fmaf(p, w, -0.00125372503f);
        p = fmaf(p, w, -0.00417768164f);
        p = fmaf(p, w, 0.246640727f);
        p = fmaf(p, w, 1.50140941f);
    } else {
        w = sqrtf(w) - 3.0f;
        p = -0.000200214257f;
        p = fmaf(p, w, 0.000100950558f);
        p = fmaf(p, w, 0.00134934322f);
        p = fmaf(p, w, -0.00367342844f);
        p = fmaf(p, w, 0.00573950773f);
        p = fmaf(p, w, -0.0076224613f);
        p = fmaf(p, w, 0.00943887047f);
        p = fmaf(p, w, 1.00167406f);
        p = fmaf(p, w, 2.83297682f);
    }
    return p * x;
}

__global__ __launch_bounds__(256) void k_sample(const float* __restrict__ mu,
                                                const float* __restrict__ lv,
                                                float* __restrict__ z) {
    int j = blockIdx.x * 256 + threadIdx.x;
    if (j >= TOT) return;
    unsigned o0, o1;
    threefry2x32(0u, (unsigned)j, o0, o1);
    unsigned bits = o0 ^ o1;
    // uniform in [minval, 1) with minval = nextafter(-1,0); scale rounds to 2.0f
    float f = __uint_as_float((bits >> 9) | 0x3f800000u) - 1.0f;
    float u = f * 2.0f - 0.99999994f;
    u = fmaxf(u, -0.99999994f);
    float eps = 1.41421356f * erfinv_f32(u);
    z[j] = fmaf(eps, expf(0.5f * lv[j]), mu[j]);
}

// ---------------- launch ----------------
extern "C" void kernel_launch(void* const* d_in, const int* in_sizes, int n_in,
                              void* d_out, int out_size, void* d_ws, size_t ws_size,
                              hipStream_t stream) {
    const float* x = (const float*)d_in[0];
    const int* ei = (const int*)d_in[1];
    const float* W1 = (const float*)d_in[2];
    const float* b1 = (const float*)d_in[3];
    const float* Wmu = (const float*)d_in[4];
    const float* bmu = (const float*)d_in[5];
    const float* Wlv = (const float*)d_in[6];
    const float* blv = (const float*)d_in[7];

    float* z = (float*)d_out;
    float* mu = z + (size_t)TOT;
    float* lv = z + 2 * (size_t)TOT;

    char* ws = (char*)d_ws;
    __hip_bfloat16* t1buf = (__hip_bfloat16*)(ws + 0ull);   // layer-1 t1
    __hip_bfloat16* habf = (__hip_bfloat16*)(ws + 0ull);    // layer-2 agg (reuses)
    int* rank = (int*)(ws + 25600000ull);                   // dead after scatter
    __hip_bfloat16* hbf = (__hip_bfloat16*)(ws + 51200000ull);
    int* counts = (int*)(ws + 76800000ull);
    int* partial = (int*)(ws + 77200000ull);
    int* bsum = (int*)(ws + 77600000ull);
    int* offsets = (int*)(ws + 77602048ull);
    __hip_bfloat16* wmu_t = (__hip_bfloat16*)(ws + 78002176ull);
    __hip_bfloat16* wlv_t = (__hip_bfloat16*)(ws + 78034944ull);
    float* dinv = (float*)(ws + 78402176ull);
    int2* sorted = (int2*)(ws + 78802176ull);

    const int* src = ei;
    const int* dst = ei + N_EDGES;

    const int NBLK = (N_NODES + 255) / 256;  // 391
    const int AGG_GRID = (N_NODES * 64 + 255) / 256;

    hipMemsetAsync(counts, 0, N_NODES * sizeof(int), stream);
    k_prep_w<<<64, 256, 0, stream>>>(Wmu, Wlv, wmu_t, wlv_t);

    // fat launch: t1 = x @ W1 (bf16) co-scheduled with the edge count/rank pass
    k_gemm1_count<<<GEMM_GRID_C + SCAT_GRID_C, 256, 0, stream>>>(
        x, W1, t1buf, dst, counts, rank);

    k_scan_block<<<NBLK, 256, 0, stream>>>(counts, partial, bsum);
    k_scan_sums<<<1, 512, 0, stream>>>(bsum, NBLK);
    k_finalize<<<NBLK, 256, 0, stream>>>(counts, partial, bsum, offsets, dinv);
    k_scatter<<<SCAT_GRID_C, 256, 0, stream>>>(src, dst, rank, offsets, dinv, sorted);

    // layer 1: h = ELU(S·t1 + b1) (bf16)
    k_agg_h<<<AGG_GRID, 256, 0, stream>>>(t1buf, offsets, sorted, dinv, b1, hbf);

    // layer 2: ha = S·h (bf16, overwrites t1/rank region); mu+lv via MFMA pair
    k_agg_bf16<<<AGG_GRID, 256, 0, stream>>>(hbf, offsets, sorted, dinv, habf);
    k_gemm_pair_mfma<<<2 * GEMM_GRID_C, 256, 0, stream>>>(habf, wmu_t, bmu, wlv_t, blv,
                                                          mu, lv);

    // z = mu + eps * exp(0.5*lv)   (eps = threefry-normal, key 42); mu/lv L3-hot
    k_sample<<<(TOT + 255) / 256, 256, 0, stream>>>(mu, lv, z);
}